// Round 13
// baseline (178.029 us; speedup 1.0000x reference)
//
#include <hip/hip_runtime.h>
#include <stdint.h>

typedef unsigned short u16;
typedef __attribute__((ext_vector_type(8))) __bf16 bf16x8;
typedef __attribute__((ext_vector_type(4))) __bf16 bf16x4;
typedef __attribute__((ext_vector_type(4))) float f32x4;
typedef __attribute__((ext_vector_type(2))) unsigned int u32x2;
typedef __attribute__((ext_vector_type(4))) unsigned int u32x4;

#define QSCALE 0.18033688011112042f /* (1/8) * log2(e) */

__device__ __forceinline__ u16 f2bf(float f) {
    uint32_t u = __builtin_bit_cast(uint32_t, f);
    u = (u + 0x7fffu + ((u >> 16) & 1u)) >> 16;
    return (u16)u;
}
__device__ __forceinline__ float bf2f(u16 h) {
    uint32_t u = ((uint32_t)h) << 16;
    return __builtin_bit_cast(float, u);
}

// async global->LDS, 16B/lane; LDS dest = wave-uniform base + lane*16.
__device__ __forceinline__ void gl_lds16(const u16* g, u16* l) {
    __builtin_amdgcn_global_load_lds(
        (__attribute__((address_space(1))) uint32_t*)(g),
        (__attribute__((address_space(3))) uint32_t*)(l), 16, 0, 0);
}

// ---- x (fp32) -> bf16, 4 elems/thread ----
__global__ __launch_bounds__(256) void convert_x_k(const float* __restrict__ xf,
                                                   u16* __restrict__ xbf) {
    const size_t v = (size_t)blockIdx.x * 256 + threadIdx.x; // float4 index
    const f32x4 val = ((const f32x4*)xf)[v];
    u32x2 p;
    p.x = (uint32_t)f2bf(val.x) | ((uint32_t)f2bf(val.y) << 16);
    p.y = (uint32_t)f2bf(val.z) | ((uint32_t)f2bf(val.w) << 16);
    *(u32x2*)&xbf[v * 4] = p;
}

// ---- weight transpose + cvt: in fp32[R][C] -> out bf16[C][R], 64x64 tiles ----
__global__ void transpose_cvt_k(const float* __restrict__ in,
                                u16* __restrict__ out, int R, int C) {
    __shared__ u16 t[64][65];
    const int bx = blockIdx.x << 6, by = blockIdx.y << 6;
    const int tx = threadIdx.x, ty = threadIdx.y; // 64 x 8
#pragma unroll
    for (int i = ty; i < 64; i += 8)
        t[i][tx] = f2bf(in[(size_t)(by + i) * C + bx + tx]);
    __syncthreads();
#pragma unroll
    for (int i = ty; i < 64; i += 8) out[(size_t)(bx + i) * R + by + tx] = t[tx][i];
}

// ---- m97-style MFMA GEMM: C = A(Mx512) * Bt^T + bias ----
// EPI 0: scatter Q(xQSCALE)/K/Vt (validated r9/r10). EPI 1: fp32 out.
template <int EPI>
__global__ __launch_bounds__(256) void gemm_bt_k(
    const u16* __restrict__ A, const u16* __restrict__ Bt,
    const float* __restrict__ bias,
    u16* __restrict__ Qb, u16* __restrict__ Kb, u16* __restrict__ Vt,
    float* __restrict__ OutF) {
    __shared__ u16 lA[128 * 32];
    __shared__ u16 lB[128 * 32];
    const int tid = threadIdx.x;
    const int w = tid >> 6, l = tid & 63, quad = l >> 4, r = l & 15;
    const int tm = blockIdx.x << 7, tn = blockIdx.y << 7;
    const int wm = (w >> 1) << 6, wn = (w & 1) << 6;
    const int srow = l >> 2, sch = (l & 3) << 3;

    f32x4 acc[4][4];
#pragma unroll
    for (int i = 0; i < 4; ++i)
#pragma unroll
        for (int j = 0; j < 4; ++j) acc[i][j] = (f32x4){0.f, 0.f, 0.f, 0.f};

    for (int kk = 0; kk < 512; kk += 32) {
        __syncthreads();
#pragma unroll
        for (int ii = 0; ii < 2; ++ii) {
            const int rowl = w * 32 + ii * 16; // wave-uniform
            gl_lds16(A + (size_t)(tm + rowl + srow) * 512 + kk + sch, &lA[rowl * 32]);
            gl_lds16(Bt + (size_t)(tn + rowl + srow) * 512 + kk + sch, &lB[rowl * 32]);
        }
        __syncthreads();
        bf16x8 af[4], bfr[4];
#pragma unroll
        for (int mi = 0; mi < 4; ++mi)
            af[mi] = *(const bf16x8*)&lA[(wm + mi * 16 + r) * 32 + quad * 8];
#pragma unroll
        for (int ni = 0; ni < 4; ++ni)
            bfr[ni] = *(const bf16x8*)&lB[(wn + ni * 16 + r) * 32 + quad * 8];
#pragma unroll
        for (int mi = 0; mi < 4; ++mi)
#pragma unroll
            for (int ni = 0; ni < 4; ++ni)
                acc[mi][ni] = __builtin_amdgcn_mfma_f32_16x16x32_bf16(
                    af[mi], bfr[ni], acc[mi][ni], 0, 0, 0);
    }

#pragma unroll
    for (int ni = 0; ni < 4; ++ni) {
        const int n = tn + wn + ni * 16 + r;
        const float bv = bias[n];
        const int which = n >> 9, head = (n >> 6) & 7, d = n & 63;
#pragma unroll
        for (int mi = 0; mi < 4; ++mi) {
#pragma unroll
            for (int i = 0; i < 4; ++i) {
                const int m = tm + wm + mi * 16 + quad * 4 + i;
                const float v = acc[mi][ni][i] + bv;
                if (EPI == 0) {
                    const int bb = m >> 11, t = m & 2047;
                    const int bh = bb * 8 + head;
                    if (which == 0)
                        Qb[((size_t)(bh * 2048 + t) << 6) + d] = f2bf(v * QSCALE);
                    else if (which == 1)
                        Kb[((size_t)(bh * 2048 + t) << 6) + d] = f2bf(v);
                    else
                        Vt[((size_t)(bh * 64 + d) << 11) + t] = f2bf(v);
                } else {
                    OutF[(size_t)m * 512 + n] = v; // fp32 out
                }
            }
        }
    }
}

// ---- MFMA flash attention v4: 128 q-rows/block, 32 q-rows/wave (2 sets) ----
// K/V LDS fragments reused across both q-sets -> ~halved LDS traffic per row.
__global__ __launch_bounds__(256) void attn_k(
    const u16* __restrict__ Qb, const u16* __restrict__ Kb,
    const u16* __restrict__ Vt, u16* __restrict__ attnb) {
    __shared__ u16 lk[64 * 64];
    __shared__ u16 lv[64 * 64];
    __shared__ u16 lp[8][16 * 72]; // [wave*2+set][qrow][kv]
    const int tid = threadIdx.x;
    const int w = tid >> 6, l = tid & 63, quad = l >> 4, r = l & 15;
    const int qt = blockIdx.x, bh = blockIdx.y;
    const size_t qbase = (size_t)bh * 2048 + qt * 128;
    const int srl = l >> 3;
    const int sg = (l & 7) ^ srl;

    // two Q fragment sets: rows w*16+r (A) and 64+w*16+r (B)
    const bf16x8 qf0a = *(const bf16x8*)&Qb[((qbase + w * 16 + r) << 6) + quad * 8];
    const bf16x8 qf1a = *(const bf16x8*)&Qb[((qbase + w * 16 + r) << 6) + 32 + quad * 8];
    const bf16x8 qf0b = *(const bf16x8*)&Qb[((qbase + 64 + w * 16 + r) << 6) + quad * 8];
    const bf16x8 qf1b = *(const bf16x8*)&Qb[((qbase + 64 + w * 16 + r) << 6) + 32 + quad * 8];

    const int rl = r & 7;
    const int rhi = r >> 3;

    const u32x4 onesu = {0x3F803F80u, 0x3F803F80u, 0x3F803F80u, 0x3F803F80u};
    const bf16x8 vones = __builtin_bit_cast(bf16x8, onesu);

    f32x4 oA[4], oB[4];
#pragma unroll
    for (int i = 0; i < 4; ++i) {
        oA[i] = (f32x4){0.f, 0.f, 0.f, 0.f};
        oB[i] = (f32x4){0.f, 0.f, 0.f, 0.f};
    }
    f32x4 osumA = (f32x4){0.f, 0.f, 0.f, 0.f};
    f32x4 osumB = (f32x4){0.f, 0.f, 0.f, 0.f};

    for (int kv0 = 0; kv0 < 2048; kv0 += 64) {
        __syncthreads();
#pragma unroll
        for (int ii = 0; ii < 2; ++ii) {
            const int chunk = w * 2 + ii;
            gl_lds16(Kb + ((size_t)(bh * 2048 + kv0 + chunk * 8 + srl) << 6) + sg * 8,
                     &lk[chunk * 512]);
            gl_lds16(Vt + (((size_t)(bh * 64 + chunk * 8 + srl)) << 11) + kv0 + sg * 8,
                     &lv[chunk * 512]);
        }
        __syncthreads();

        // S^T tiles for both q-sets; K fragments read ONCE, used twice
#pragma unroll
        for (int kt = 0; kt < 4; ++kt) {
            const int base = (kt * 2 + rhi) * 512 + rl * 64;
            const bf16x8 a0 = *(const bf16x8*)&lk[base + (quad ^ rl) * 8];
            const bf16x8 a1 = *(const bf16x8*)&lk[base + ((quad ^ rl) ^ 4) * 8];
            f32x4 za = (f32x4){0.f, 0.f, 0.f, 0.f};
            f32x4 zb = (f32x4){0.f, 0.f, 0.f, 0.f};
            za = __builtin_amdgcn_mfma_f32_16x16x32_bf16(a0, qf0a, za, 0, 0, 0);
            za = __builtin_amdgcn_mfma_f32_16x16x32_bf16(a1, qf1a, za, 0, 0, 0);
            zb = __builtin_amdgcn_mfma_f32_16x16x32_bf16(a0, qf0b, zb, 0, 0, 0);
            zb = __builtin_amdgcn_mfma_f32_16x16x32_bf16(a1, qf1b, zb, 0, 0, 0);
#pragma unroll
            for (int set = 0; set < 2; ++set) {
                const f32x4 z = set ? zb : za;
                const uint32_t u0 =
                    __builtin_bit_cast(uint32_t, __builtin_amdgcn_exp2f(z[0])) + 0x8000u;
                const uint32_t u1 =
                    __builtin_bit_cast(uint32_t, __builtin_amdgcn_exp2f(z[1])) + 0x8000u;
                const uint32_t u2 =
                    __builtin_bit_cast(uint32_t, __builtin_amdgcn_exp2f(z[2])) + 0x8000u;
                const uint32_t u3 =
                    __builtin_bit_cast(uint32_t, __builtin_amdgcn_exp2f(z[3])) + 0x8000u;
                const uint32_t lo = __builtin_amdgcn_perm(u1, u0, 0x07060302u);
                const uint32_t hi = __builtin_amdgcn_perm(u3, u2, 0x07060302u);
                const uint64_t both = (uint64_t)lo | ((uint64_t)hi << 32);
                *(bf16x4*)&lp[(w << 1) | set][r * 72 + kt * 16 + quad * 4] =
                    __builtin_bit_cast(bf16x4, both);
            }
        }

        // drain P ds_writes; block compiler reordering of the P reads
        asm volatile("s_waitcnt lgkmcnt(0)" ::: "memory");

        // PV: V fragments read ONCE, used for both q-sets; + ones row sums
#pragma unroll
        for (int h = 0; h < 2; ++h) {
            const bf16x8 apA = *(const bf16x8*)&lp[w << 1][r * 72 + h * 32 + quad * 8];
            const bf16x8 apB =
                *(const bf16x8*)&lp[(w << 1) | 1][r * 72 + h * 32 + quad * 8];
#pragma unroll
            for (int dt = 0; dt < 4; ++dt) {
                const int baseV = (dt * 2 + rhi) * 512 + rl * 64;
                const bf16x8 bv =
                    *(const bf16x8*)&lv[baseV + ((h * 4 + quad) ^ rl) * 8];
                oA[dt] = __builtin_amdgcn_mfma_f32_16x16x32_bf16(apA, bv, oA[dt], 0, 0, 0);
                oB[dt] = __builtin_amdgcn_mfma_f32_16x16x32_bf16(apB, bv, oB[dt], 0, 0, 0);
            }
            osumA = __builtin_amdgcn_mfma_f32_16x16x32_bf16(apA, vones, osumA, 0, 0, 0);
            osumB = __builtin_amdgcn_mfma_f32_16x16x32_bf16(apB, vones, osumB, 0, 0, 0);
        }
    }

    const int bb = bh >> 3, head = bh & 7;
#pragma unroll
    for (int set = 0; set < 2; ++set) {
        const f32x4* o = set ? oB : oA;
        const f32x4 osum = set ? osumB : osumA;
#pragma unroll
        for (int i = 0; i < 4; ++i) {
            const float inv = __builtin_amdgcn_rcpf(osum[i]);
            const int row =
                bb * 2048 + qt * 128 + set * 64 + w * 16 + quad * 4 + i;
#pragma unroll
            for (int dt = 0; dt < 4; ++dt)
                attnb[(size_t)row * 512 + head * 64 + dt * 16 + r] =
                    f2bf(o[dt][i] * inv);
        }
    }
}

// ---------------- launch ----------------
extern "C" void kernel_launch(void* const* d_in, const int* in_sizes, int n_in,
                              void* d_out, int out_size, void* d_ws, size_t ws_size,
                              hipStream_t stream) {
    const float *x = nullptr, *wq = nullptr, *bq = nullptr, *wp = nullptr, *bp = nullptr;
    for (int i = 0; i < n_in; ++i) {
        switch (in_sizes[i]) {
            case 4194304: x  = (const float*)d_in[i]; break;
            case 786432:  wq = (const float*)d_in[i]; break;
            case 1536:    bq = (const float*)d_in[i]; break;
            case 262144:  wp = (const float*)d_in[i]; break;
            case 512:     bp = (const float*)d_in[i]; break;
        }
    }
    if (!x || !wq || !bq || !wp || !bp) {
        x = (const float*)d_in[0]; wq = (const float*)d_in[1];
        bq = (const float*)d_in[2]; wp = (const float*)d_in[3];
        bp = (const float*)d_in[4];
    }
    float* out = (float*)d_out;

    // ws plan (32 MiB): attnb@0 (wqkvT aliases until attn), Qb@8M (wprojT
    // aliases after attn), Kb@16M, Vt@24M. xbf lives in d_out until proj.
    char* ws = (char*)d_ws;
    u16* attnb  = (u16*)(ws + 0);
    u16* wqkvT  = (u16*)(ws + 0);
    u16* Qb     = (u16*)(ws + 8388608);
    u16* wprojT = (u16*)(ws + 8388608);
    u16* Kb     = (u16*)(ws + 16777216);
    u16* Vt     = (u16*)(ws + 25165824);
    u16* xbf    = (u16*)d_out;

    convert_x_k<<<dim3(4096), 256, 0, stream>>>(x, xbf);
    transpose_cvt_k<<<dim3(24, 8), dim3(64, 8), 0, stream>>>(wq, wqkvT, 512, 1536);
    gemm_bt_k<0><<<dim3(64, 12), 256, 0, stream>>>(xbf, wqkvT, bq, Qb, Kb, Vt, nullptr);
    attn_k<<<dim3(16, 32), 256, 0, stream>>>(Qb, Kb, Vt, attnb);
    transpose_cvt_k<<<dim3(8, 8), dim3(64, 8), 0, stream>>>(wp, wprojT, 512, 512);
    gemm_bt_k<1><<<dim3(64, 4), 256, 0, stream>>>(attnb, wprojT, bp, nullptr, nullptr,
                                                  nullptr, out);
}